// Round 4
// baseline (1299.662 us; speedup 1.0000x reference)
//
#include <hip/hip_runtime.h>
#include <cmath>

#define B_  128
#define T_  512
#define E_  128
#define H_  128
#define G4  512   // 4*H
#define K_  9
#define PADK 136  // LDS row stride in shorts (272 B -> 2-way bank aliasing, free)

typedef __attribute__((ext_vector_type(8)))  short short8;
typedef __attribute__((ext_vector_type(4)))  float f32x4;
typedef __attribute__((ext_vector_type(32))) float f32x32;

__device__ __forceinline__ unsigned short bf16_rnd(float x) {
  return (unsigned short)((__float_as_uint(x) + 0x8000u) >> 16);
}
__device__ __forceinline__ float bf16_val(unsigned short b) {
  return __uint_as_float(((unsigned int)b) << 16);
}

// ---------------------------------------------------------------------------
// Kernel 0: pre-split Wih (both dirs) into hi/lo bf16, laid out in MFMA
// B-fragment order: for (gg=dir*8+g, nf, kf, plane, lane, j):
//   n = g*64+nf*16+(lane&15), k = kf*32+(lane>>4)*8+j
//   offset_shorts = ((gg*16 + nf*4 + kf)*2 + plane)*512 + lane*8
// Also folds bih+bhh into bsum[dir*512+n]. 512 KB total, L2-resident.
// ---------------------------------------------------------------------------
__global__ __launch_bounds__(256)
void prep_weights(const float* __restrict__ Wif, const float* __restrict__ Wib,
                  const float* __restrict__ bif, const float* __restrict__ bhf,
                  const float* __restrict__ bib, const float* __restrict__ bhb,
                  unsigned short* __restrict__ wswz, float* __restrict__ bsum)
{
  const int u    = blockIdx.x * 256 + threadIdx.x;   // 0..16383
  const int lane = u & 63;
  const int kf   = (u >> 6) & 3;
  const int nf   = (u >> 8) & 3;
  const int g    = (u >> 10) & 7;
  const int dir  = (u >> 13) & 1;
  const float* W = dir ? Wib : Wif;
  const int n  = g * 64 + nf * 16 + (lane & 15);
  const int k0 = kf * 32 + ((lane >> 4) << 3);
  const float* src = W + (size_t)n * E_ + k0;
  const int gg = dir * 8 + g;
  unsigned short* dsth = wswz + (size_t)((gg * 16 + nf * 4 + kf) * 2 + 0) * 512 + lane * 8;
  unsigned short* dstl = wswz + (size_t)((gg * 16 + nf * 4 + kf) * 2 + 1) * 512 + lane * 8;
#pragma unroll
  for (int j = 0; j < 8; ++j) {
    float v = src[j];
    unsigned short h = bf16_rnd(v);
    dsth[j] = h;
    dstl[j] = bf16_rnd(v - bf16_val(h));
  }
  if (u < 1024) {
    const int d2 = u >> 9, nn = u & 511;
    bsum[u] = (d2 ? bib[nn] : bif[nn]) + (d2 ? bhb[nn] : bhf[nn]);
  }
}

// ---------------------------------------------------------------------------
// Kernel 1 (v4): split-bf16 MFMA projection. Block = 64 m-rows of ONE dir;
// stages gathered A once (hi/lo in LDS, 34 KB), loops all 8 n-groups reading
// pre-swizzled B-fragments straight from global (L2) -> no per-tile A
// redundancy (was 16x), no B conversion, one barrier per block.
// C/D layout: col=lane&15, row=(lane>>4)*4+reg (m89-verified, round-3 pass).
// ---------------------------------------------------------------------------
__global__ __launch_bounds__(256, 2)
void proj_mfma2(const int* __restrict__ sent, const float* __restrict__ embed,
                const unsigned short* __restrict__ wswz, const float* __restrict__ bsum,
                float* __restrict__ proj, int t0f, int Tc, int tcshift)
{
  __shared__ unsigned short As[2 * 64 * PADK];   // plane 0 = hi, 1 = lo
  const int tid = threadIdx.x;
  const int dir = blockIdx.y;
  const int m0  = blockIdx.x << 6;
  const int t0  = dir ? (T_ - t0f - Tc) : t0f;
  const int tcm = Tc - 1;

  // ---- stage A: 4 threads per row, each converts 32 fp32 -> hi/lo bf16
  {
    const int r   = tid >> 2;
    const int seg = (tid & 3) << 5;
    const int rr  = m0 + r;
    const int b   = rr >> tcshift;
    const int t   = t0 + (rr & tcm);
    const int vid = sent[b * T_ + t];
    const float* arow = embed + (size_t)vid * E_ + seg;
    unsigned short* ah = As + r * PADK + seg;
    unsigned short* al = ah + 64 * PADK;
#pragma unroll
    for (int q = 0; q < 32; q += 4) {
      float4 av = *(const float4*)(arow + q);
      ushort4 vh, vl;
      vh.x = bf16_rnd(av.x); vl.x = bf16_rnd(av.x - bf16_val(vh.x));
      vh.y = bf16_rnd(av.y); vl.y = bf16_rnd(av.y - bf16_val(vh.y));
      vh.z = bf16_rnd(av.z); vl.z = bf16_rnd(av.z - bf16_val(vh.z));
      vh.w = bf16_rnd(av.w); vl.w = bf16_rnd(av.w - bf16_val(vh.w));
      *(ushort4*)(ah + q) = vh; *(ushort4*)(al + q) = vl;
    }
  }
  __syncthreads();

  const int lane = tid & 63;
  const int wv   = tid >> 6;
  const int frow = lane & 15;
  const int kq   = (lane >> 4) << 3;
  const unsigned short* Ab = As + (wv * 16 + frow) * PADK + kq;
  short8 ahf[4], alf[4];                 // A fragments, resident for the block
#pragma unroll
  for (int kf = 0; kf < 4; ++kf) {
    ahf[kf] = *(const short8*)(Ab + kf * 32);
    alf[kf] = *(const short8*)(Ab + 64 * PADK + kf * 32);
  }

  const int coln = lane & 15;
  const int rowb = m0 + wv * 16 + ((lane >> 4) << 2);
  const unsigned short* wbase = wswz + (size_t)dir * 131072;   // 8 groups * 16384

  for (int g = 0; g < 8; ++g) {
    const unsigned short* bgrp = wbase + (size_t)g * 16384 + lane * 8;
    f32x4 acc[4] = {};
#pragma unroll
    for (int kf = 0; kf < 4; ++kf) {
      short8 bh[4], bl[4];
#pragma unroll
      for (int nf = 0; nf < 4; ++nf) {
        bh[nf] = *(const short8*)(bgrp + (size_t)((nf * 4 + kf) * 2 + 0) * 512);
        bl[nf] = *(const short8*)(bgrp + (size_t)((nf * 4 + kf) * 2 + 1) * 512);
      }
#pragma unroll
      for (int nf = 0; nf < 4; ++nf)
        acc[nf] = __builtin_amdgcn_mfma_f32_16x16x32_bf16(ahf[kf], bh[nf], acc[nf], 0, 0, 0);
#pragma unroll
      for (int nf = 0; nf < 4; ++nf)
        acc[nf] = __builtin_amdgcn_mfma_f32_16x16x32_bf16(ahf[kf], bl[nf], acc[nf], 0, 0, 0);
#pragma unroll
      for (int nf = 0; nf < 4; ++nf)
        acc[nf] = __builtin_amdgcn_mfma_f32_16x16x32_bf16(alf[kf], bh[nf], acc[nf], 0, 0, 0);
    }
#pragma unroll
    for (int nf = 0; nf < 4; ++nf) {
      const int n = g * 64 + nf * 16 + coln;
      const float bias = bsum[dir * G4 + n];
#pragma unroll
      for (int rg = 0; rg < 4; ++rg)
        proj[(size_t)(rowb + rg) * 1024 + dir * G4 + n] = acc[nf][rg] + bias;
    }
  }
}

// ---------------------------------------------------------------------------
// Kernel 2 (v3): LSTM recurrence. 256 threads; thread owns gate rows tid and
// tid+256. Whh rows held as 8x f32x32 ext-vector SSA values (256 VGPRs) --
// arrays were demoted to scratch/AGPR in v1/v2 (VGPR_Count 84/140), this
// forces true residency. h broadcast via wave-uniform ds_read_b128 (DS pipe,
// overlaps the v_fmac stream). launch_bounds(256,1): 512-VGPR budget.
// ---------------------------------------------------------------------------
#define LOADW(vec, ptr) { _Pragma("unroll") for (int q = 0; q < 8; ++q) { \
    float4 t4 = *(const float4*)((ptr) + 4 * q); \
    vec[4*q] = t4.x; vec[4*q+1] = t4.y; vec[4*q+2] = t4.z; vec[4*q+3] = t4.w; } }

#define FMAQ(vecA, vecB, hbase) { _Pragma("unroll") for (int q = 0; q < 8; ++q) { \
    float4 hv = *(const float4*)&h_lds[(hbase) + 4 * q]; \
    acc0 += hv.x * vecA[4*q];   acc1 += hv.x * vecB[4*q]; \
    acc0 += hv.y * vecA[4*q+1]; acc1 += hv.y * vecB[4*q+1]; \
    acc0 += hv.z * vecA[4*q+2]; acc1 += hv.z * vecB[4*q+2]; \
    acc0 += hv.w * vecA[4*q+3]; acc1 += hv.w * vecB[4*q+3]; } }

__global__ __launch_bounds__(256, 1)
void lstm_chunk3(const float* __restrict__ proj,
                 const float* __restrict__ Whf, const float* __restrict__ Whb,
                 const int* __restrict__ lengths,
                 float* __restrict__ hs,
                 float* __restrict__ sh, float* __restrict__ sc,
                 int t0f, int Tc, int first)
{
  const int dir = blockIdx.x;
  const int b   = blockIdx.y;
  const int tid = threadIdx.x;             // 0..255
  const float* __restrict__ Whh = dir ? Whb : Whf;
  __shared__ __align__(16) float h_lds[H_];
  __shared__ float gates[G4];

  f32x32 wA0, wA1, wA2, wA3, wB0, wB1, wB2, wB3;
  {
    const float* r0 = Whh + (size_t)tid * H_;
    const float* r1 = Whh + (size_t)(tid + 256) * H_;
    LOADW(wA0, r0);      LOADW(wA1, r0 + 32); LOADW(wA2, r0 + 64); LOADW(wA3, r0 + 96);
    LOADW(wB0, r1);      LOADW(wB1, r1 + 32); LOADW(wB2, r1 + 64); LOADW(wB3, r1 + 96);
  }
  const int len = lengths[b];
  const int t0  = dir ? (T_ - t0f - Tc) : t0f;
  float c = 0.f, hval = 0.f;
  if (tid < H_) {
    if (!first) {
      hval = sh[(dir * B_ + b) * H_ + tid];
      c    = sc[(dir * B_ + b) * H_ + tid];
    }
    h_lds[tid] = hval;
  }
  __syncthreads();

  const float* p0 = proj + (size_t)b * Tc * 1024 + dir * G4 + tid;
  const float* p1 = p0 + 256;
  const int stp = dir ? -1 : 1;
  int tc = dir ? (Tc - 1) : 0;
  float f0 = p0[(size_t)tc * 1024], f1 = p1[(size_t)tc * 1024];

  for (int s = 0; s < Tc; ++s) {
    const int t = t0 + tc;
    float acc0 = f0, acc1 = f1;
    int tcn = tc + stp;
    int tcl = tcn < 0 ? 0 : (tcn > Tc - 1 ? Tc - 1 : tcn);   // prefetch next
    f0 = p0[(size_t)tcl * 1024]; f1 = p1[(size_t)tcl * 1024];
    FMAQ(wA0, wB0, 0);  FMAQ(wA1, wB1, 32);
    FMAQ(wA2, wB2, 64); FMAQ(wA3, wB3, 96);
    gates[tid]       = 1.f / (1.f + expf(-acc0));                              // i or f
    gates[tid + 256] = (tid < 128) ? tanhf(acc1) : 1.f / (1.f + expf(-acc1));  // g or o
    __syncthreads();
    if (tid < H_) {
      float gi = gates[tid], gf = gates[tid + 128];
      float gg = gates[tid + 256], go = gates[tid + 384];
      float cn = gf * c + gi * gg;
      float hn = go * tanhf(cn);
      bool  m  = (t < len);
      c    = m ? cn : c;
      hval = m ? hn : hval;
      h_lds[tid] = hval;
      hs[(size_t)(b * T_ + t) * 256 + dir * H_ + tid] = m ? hn : 0.f;
    }
    __syncthreads();
    tc = tcn;
  }
  if (tid < H_) {
    sh[(dir * B_ + b) * H_ + tid] = hval;
    sc[(dir * B_ + b) * H_ + tid] = c;
  }
}

// ---------------------------------------------------------------------------
// Kernel 3: emissions em[m][k] = hs[m][:] . W_out[k][:] + b_out[k]
// ---------------------------------------------------------------------------
__global__ __launch_bounds__(256)
void emis_kernel(const float* __restrict__ hs, const float* __restrict__ Wout,
                 const float* __restrict__ bout, float* __restrict__ em)
{
  __shared__ __align__(16) float Wl[K_ * 256];
  const int tid = threadIdx.x;
  for (int i = tid; i < K_ * 256; i += 256) Wl[i] = Wout[i];
  __syncthreads();
  const int m = blockIdx.x * 256 + tid;
  const float* h = hs + (size_t)m * 256;
  float acc[K_] = {};
#pragma unroll 4
  for (int kk = 0; kk < 64; ++kk) {
    float4 h4 = *(const float4*)(h + kk * 4);
#pragma unroll
    for (int k9 = 0; k9 < K_; ++k9) {
      float4 w4 = *(const float4*)&Wl[k9 * 256 + kk * 4];
      acc[k9] += h4.x * w4.x + h4.y * w4.y + h4.z * w4.z + h4.w * w4.w;
    }
  }
#pragma unroll
  for (int k9 = 0; k9 < K_; ++k9) em[(size_t)m * K_ + k9] = acc[k9] + bout[k9];
}

// ---------------------------------------------------------------------------
// Kernel 4: Viterbi decode, one 64-lane wave per batch element.
// ---------------------------------------------------------------------------
__global__ __launch_bounds__(64)
void viterbi_kernel(const float* __restrict__ em, const int* __restrict__ lengths,
                    const float* __restrict__ st, const float* __restrict__ en,
                    const float* __restrict__ trans, int* __restrict__ tags)
{
  const int b    = blockIdx.x;
  const int lane = threadIdx.x;
  __shared__ unsigned char hist[(T_ - 1) * 16];
  const int len = lengths[b];
  float tr[K_];
#pragma unroll
  for (int j = 0; j < K_; ++j) tr[j] = (lane < K_) ? trans[j * K_ + lane] : 0.f;
  float s = (lane < K_) ? st[lane] + em[(size_t)(b * T_) * K_ + lane] : -1e30f;
  for (int t = 1; t < len; ++t) {
    float best = -1e30f; int bj = 0;
#pragma unroll
    for (int j = 0; j < K_; ++j) {
      float v = __shfl(s, j) + tr[j];
      if (v > best) { best = v; bj = j; }    // strict > == first-max (argmax)
    }
    if (lane < K_) {
      s = best + em[(size_t)(b * T_ + t) * K_ + lane];
      hist[(t - 1) * 16 + lane] = (unsigned char)bj;
    }
  }
  float fs = (lane < K_) ? s + en[lane] : -1e30f;
  float best = -1e30f; int last = 0;
#pragma unroll
  for (int j = 0; j < K_; ++j) {
    float v = __shfl(fs, j);
    if (v > best) { best = v; last = j; }
  }
  __syncthreads();                            // hist visible to lane 0
  if (lane == 0) {
    int tag = last;
    tags[b * T_ + len - 1] = tag;
    for (int t = len - 2; t >= 0; --t) {
      tag = hist[t * 16 + tag];
      tags[b * T_ + t] = tag;
    }
  }
  for (int t = len + lane; t < T_; t += 64) tags[b * T_ + t] = 0;
}

// ---------------------------------------------------------------------------
extern "C" void kernel_launch(void* const* d_in, const int* in_sizes, int n_in,
                              void* d_out, int out_size, void* d_ws, size_t ws_size,
                              hipStream_t stream)
{
  const int*   sent  = (const int*)d_in[0];
  const int*   lens  = (const int*)d_in[1];
  const float* embed = (const float*)d_in[2];
  const float* Wif   = (const float*)d_in[3];
  const float* Whf   = (const float*)d_in[4];
  const float* bif   = (const float*)d_in[5];
  const float* bhf   = (const float*)d_in[6];
  const float* Wib   = (const float*)d_in[7];
  const float* Whb   = (const float*)d_in[8];
  const float* bib   = (const float*)d_in[9];
  const float* bhb   = (const float*)d_in[10];
  const float* Wout  = (const float*)d_in[11];
  const float* bout  = (const float*)d_in[12];
  const float* stt   = (const float*)d_in[13];
  const float* ent   = (const float*)d_in[14];
  const float* trans = (const float*)d_in[15];
  int* tags = (int*)d_out;

  // workspace layout (floats): hs | em | sh | sc | wswz | bsum | proj(chunk)
  float* ws   = (float*)d_ws;
  float* hs   = ws;                                  // B*T*256   (67.1 MB)
  float* em   = hs + (size_t)B_ * T_ * 256;          // B*T*9     ( 2.4 MB)
  float* sh   = em + (size_t)B_ * T_ * K_;
  float* sc   = sh + (size_t)2 * B_ * H_;
  unsigned short* wswz = (unsigned short*)(sc + (size_t)2 * B_ * H_);  // 262144 shorts
  float* bsum = (float*)(wswz + 262144);             // 1024 floats
  float* proj = bsum + 1024;
  const size_t fixed_bytes = (size_t)((char*)proj - (char*)ws);

  // largest time-chunk whose proj buffer fits the workspace (floor at 64)
  int Tc = 512, tcshift = 9;
  while (Tc > 64 && fixed_bytes + (size_t)B_ * Tc * 1024 * sizeof(float) > ws_size) {
    Tc >>= 1; tcshift--;
  }

  hipLaunchKernelGGL(prep_weights, dim3(64), dim3(256), 0, stream,
                     Wif, Wib, bif, bhf, bib, bhb, wswz, bsum);

  const int nch = T_ / Tc;
  for (int c2 = 0; c2 < nch; ++c2) {
    const int t0f = c2 * Tc;
    dim3 g1((B_ * Tc) >> 6, 2);
    hipLaunchKernelGGL(proj_mfma2, g1, dim3(256), 0, stream,
                       sent, embed, wswz, bsum, proj, t0f, Tc, tcshift);
    dim3 g2(2, B_);
    hipLaunchKernelGGL(lstm_chunk3, g2, dim3(256), 0, stream,
                       proj, Whf, Whb, lens, hs, sh, sc, t0f, Tc, (int)(c2 == 0));
  }
  hipLaunchKernelGGL(emis_kernel, dim3((B_ * T_) / 256), dim3(256), 0, stream,
                     hs, Wout, bout, em);
  hipLaunchKernelGGL(viterbi_kernel, dim3(B_), dim3(64), 0, stream,
                     em, lens, stt, ent, trans, tags);
}

// Round 5
// 1099.988 us; speedup vs baseline: 1.1815x; 1.1815x over previous
//
#include <hip/hip_runtime.h>
#include <cmath>

#define B_  128
#define T_  512
#define E_  128
#define H_  128
#define G4  512   // 4*H
#define K_  9

typedef __attribute__((ext_vector_type(8))) short short8;
typedef __attribute__((ext_vector_type(4))) float f32x4;

__device__ __forceinline__ unsigned short bf16_rnd(float x) {
  return (unsigned short)((__float_as_uint(x) + 0x8000u) >> 16);
}
__device__ __forceinline__ float bf16_val(unsigned short b) {
  return __uint_as_float(((unsigned int)b) << 16);
}
// split 8 consecutive floats into hi/lo bf16 fragments
__device__ __forceinline__ void split8(const float* p, short8& hi, short8& lo) {
  float4 a = *(const float4*)p;
  float4 b = *(const float4*)(p + 4);
  float v[8] = {a.x, a.y, a.z, a.w, b.x, b.y, b.z, b.w};
#pragma unroll
  for (int j = 0; j < 8; ++j) {
    unsigned short h = bf16_rnd(v[j]);
    hi[j] = (short)h;
    lo[j] = (short)bf16_rnd(v[j] - bf16_val(h));
  }
}

// ---------------------------------------------------------------------------
// Kernel 0: pre-split Wih AND Whh (both dirs) into hi/lo bf16 in MFMA
// B-fragment order (r3/r4-verified producer/consumer pairing):
//   n = g*64+nf*16+(lane&15), k = kf*32+(lane>>4)*8+j
//   offset_shorts = dir*131072 + g*16384 + ((nf*4+kf)*2+plane)*512 + lane*8+j
// u bit14 selects matrix (0=Wih -> wswz, 1=Whh -> wswz+262144).
// Also folds bih+bhh into bsum[dir*512+n]. 1 MB total, L2-resident.
// ---------------------------------------------------------------------------
__global__ __launch_bounds__(256)
void prep_weights(const float* __restrict__ Wif, const float* __restrict__ Wib,
                  const float* __restrict__ Whf, const float* __restrict__ Whb,
                  const float* __restrict__ bif, const float* __restrict__ bhf,
                  const float* __restrict__ bib, const float* __restrict__ bhb,
                  unsigned short* __restrict__ wswz, float* __restrict__ bsum)
{
  const int u    = blockIdx.x * 256 + threadIdx.x;   // 0..32767
  const int lane = u & 63;
  const int kf   = (u >> 6) & 3;
  const int nf   = (u >> 8) & 3;
  const int g    = (u >> 10) & 7;
  const int dir  = (u >> 13) & 1;
  const int mat  = (u >> 14) & 1;
  const float* W = mat ? (dir ? Whb : Whf) : (dir ? Wib : Wif);
  const int n  = g * 64 + nf * 16 + (lane & 15);
  const int k0 = kf * 32 + ((lane >> 4) << 3);
  const float* src = W + (size_t)n * E_ + k0;
  unsigned short* base = wswz + (size_t)mat * 262144 + (size_t)dir * 131072
                       + (size_t)g * 16384;
  unsigned short* dsth = base + (size_t)((nf * 4 + kf) * 2 + 0) * 512 + lane * 8;
  unsigned short* dstl = base + (size_t)((nf * 4 + kf) * 2 + 1) * 512 + lane * 8;
#pragma unroll
  for (int j = 0; j < 8; ++j) {
    float v = src[j];
    unsigned short h = bf16_rnd(v);
    dsth[j] = h;
    dstl[j] = bf16_rnd(v - bf16_val(h));
  }
  if (u < 1024) {
    const int d2 = u >> 9, nn = u & 511;
    bsum[u] = (d2 ? bib[nn] : bif[nn]) + (d2 ? bhb[nn] : bhf[nn]);
  }
}

// ---------------------------------------------------------------------------
// Kernel 1 (v5): split-bf16 MFMA projection, ZERO LDS / ZERO barriers.
// Block = 256 m-rows of one dir (wave w owns rows [64w,64w+64)). A-fragments
// (gathered embed rows) load straight from global: for a given (ms,kf) the
// 4 quads of 16 lanes read 128 contiguous bytes of one row -> merged
// segments, each element fetched exactly once. B pre-swizzled (L2).
// C/D layout: col=lane&15, row=(lane>>4)*4+reg (verified r3/r4).
// ---------------------------------------------------------------------------
__global__ __launch_bounds__(256, 1)
void proj_mfma4(const int* __restrict__ sent, const float* __restrict__ embed,
                const unsigned short* __restrict__ wih_swz,
                const float* __restrict__ bsum,
                float* __restrict__ proj, int t0f, int Tc, int tcshift)
{
  const int tid = threadIdx.x, lane = tid & 63, wv = tid >> 6;
  const int dir = blockIdx.y;
  const int m0  = blockIdx.x << 8;
  const int t0  = dir ? (T_ - t0f - Tc) : t0f;
  const int tcm = Tc - 1;
  const int fr  = lane & 15;
  const int kq  = (lane >> 4) << 3;

  short8 ahf[4][4], alf[4][4];           // [ms][kf], -> AGPR, MFMA-native
#pragma unroll
  for (int ms = 0; ms < 4; ++ms) {
    const int rr = m0 + wv * 64 + ms * 16 + fr;
    const int b  = rr >> tcshift;
    const int t  = t0 + (rr & tcm);
    const int vid = sent[b * T_ + t];
    const float* arow = embed + (size_t)vid * E_ + kq;
#pragma unroll
    for (int kf = 0; kf < 4; ++kf)
      split8(arow + kf * 32, ahf[ms][kf], alf[ms][kf]);
  }

  const int rowq = m0 + wv * 64 + ((lane >> 4) << 2);
  for (int g = 0; g < 8; ++g) {
    const unsigned short* bgrp = wih_swz + (size_t)dir * 131072
                               + (size_t)g * 16384 + lane * 8;
    short8 bh[4][4], bl[4][4];
#pragma unroll
    for (int nf = 0; nf < 4; ++nf)
#pragma unroll
      for (int kf = 0; kf < 4; ++kf) {
        bh[nf][kf] = *(const short8*)(bgrp + (size_t)((nf * 4 + kf) * 2 + 0) * 512);
        bl[nf][kf] = *(const short8*)(bgrp + (size_t)((nf * 4 + kf) * 2 + 1) * 512);
      }
    f32x4 acc[4][4] = {};
#pragma unroll
    for (int kf = 0; kf < 4; ++kf)
#pragma unroll
      for (int ms = 0; ms < 4; ++ms)
#pragma unroll
        for (int nf = 0; nf < 4; ++nf)
          acc[ms][nf] = __builtin_amdgcn_mfma_f32_16x16x32_bf16(ahf[ms][kf], bh[nf][kf], acc[ms][nf], 0, 0, 0);
#pragma unroll
    for (int kf = 0; kf < 4; ++kf)
#pragma unroll
      for (int ms = 0; ms < 4; ++ms)
#pragma unroll
        for (int nf = 0; nf < 4; ++nf)
          acc[ms][nf] = __builtin_amdgcn_mfma_f32_16x16x32_bf16(ahf[ms][kf], bl[nf][kf], acc[ms][nf], 0, 0, 0);
#pragma unroll
    for (int kf = 0; kf < 4; ++kf)
#pragma unroll
      for (int ms = 0; ms < 4; ++ms)
#pragma unroll
        for (int nf = 0; nf < 4; ++nf)
          acc[ms][nf] = __builtin_amdgcn_mfma_f32_16x16x32_bf16(alf[ms][kf], bh[nf][kf], acc[ms][nf], 0, 0, 0);
#pragma unroll
    for (int nf = 0; nf < 4; ++nf) {
      const int n = g * 64 + nf * 16 + fr;
      const float bias = bsum[dir * G4 + n];
#pragma unroll
      for (int ms = 0; ms < 4; ++ms)
#pragma unroll
        for (int rg = 0; rg < 4; ++rg)
          proj[(size_t)(rowq + ms * 16 + rg) * 1024 + dir * G4 + n] = acc[ms][nf][rg] + bias;
    }
  }
}

// ---------------------------------------------------------------------------
// Kernel 2 (v5): MFMA LSTM recurrence. One block (512 thr, 8 waves) per
// (dir,b) chain. Wave w owns gate rows n in [64w,64w+64); its Whh
// B-fragments (32 short8 = 128 regs) sit in AGPRs -- MFMA reads them
// natively, so residency costs nothing (the r1-r4 VALU/AGPR trap).
// h is replicated across all 16 A-rows (A depends only on k), so every
// lane's D value is valid; lanes 0..15 carry the gate row.
// Per step: 48 MFMA/wave (~466 cyc/SIMD on the matrix pipe) + 2 barriers.
// ---------------------------------------------------------------------------
__global__ __launch_bounds__(512, 2)
void lstm_mfma(const float* __restrict__ proj,
               const unsigned short* __restrict__ whh_swz,
               const int* __restrict__ lengths, float* __restrict__ hs,
               float* __restrict__ sh, float* __restrict__ sc,
               int t0f, int Tc, int first)
{
  const int dir = blockIdx.x, b = blockIdx.y;
  const int tid = threadIdx.x, lane = tid & 63, wv = tid >> 6;
  __shared__ float gates[G4];
  __shared__ float h32[H_];
  __shared__ __align__(16) unsigned short hhi[H_];
  __shared__ __align__(16) unsigned short hlo[H_];

  const unsigned short* bgrp = whh_swz + (size_t)dir * 131072
                             + (size_t)wv * 16384 + lane * 8;
  short8 bh[4][4], bl[4][4];
#pragma unroll
  for (int nf = 0; nf < 4; ++nf)
#pragma unroll
    for (int kf = 0; kf < 4; ++kf) {
      bh[nf][kf] = *(const short8*)(bgrp + (size_t)((nf * 4 + kf) * 2 + 0) * 512);
      bl[nf][kf] = *(const short8*)(bgrp + (size_t)((nf * 4 + kf) * 2 + 1) * 512);
    }

  const int len = lengths[b];
  const int t0  = dir ? (T_ - t0f - Tc) : t0f;
  float c = 0.f;
  if (tid < H_) {
    float hv = 0.f;
    if (!first) {
      hv = sh[(dir * B_ + b) * H_ + tid];
      c  = sc[(dir * B_ + b) * H_ + tid];
    }
    h32[tid] = hv;
    unsigned short hi = bf16_rnd(hv);
    hhi[tid] = hi;
    hlo[tid] = bf16_rnd(hv - bf16_val(hi));
  }
  __syncthreads();

  const int  kq  = (lane >> 4) << 3;
  const bool isg = (wv == 4) || (wv == 5);   // g-gate rows -> tanh
  const int  stp = dir ? -1 : 1;
  int tc = dir ? (Tc - 1) : 0;
  const float* pbase = proj + (size_t)b * Tc * 1024 + dir * G4 + wv * 64;

  for (int s = 0; s < Tc; ++s) {
    const int t = t0 + tc;
    float pj0 = 0.f, pj1 = 0.f, pj2 = 0.f, pj3 = 0.f;
    if (lane < 16) {
      const float* pp = pbase + (size_t)tc * 1024 + lane;
      pj0 = pp[0]; pj1 = pp[16]; pj2 = pp[32]; pj3 = pp[48];
    }
    short8 ah[4], al[4];
#pragma unroll
    for (int kf = 0; kf < 4; ++kf) {
      ah[kf] = *(const short8*)(hhi + kf * 32 + kq);
      al[kf] = *(const short8*)(hlo + kf * 32 + kq);
    }
    f32x4 acc[4] = {};
#pragma unroll
    for (int kf = 0; kf < 4; ++kf)
#pragma unroll
      for (int nf = 0; nf < 4; ++nf)
        acc[nf] = __builtin_amdgcn_mfma_f32_16x16x32_bf16(ah[kf], bh[nf][kf], acc[nf], 0, 0, 0);
#pragma unroll
    for (int kf = 0; kf < 4; ++kf)
#pragma unroll
      for (int nf = 0; nf < 4; ++nf)
        acc[nf] = __builtin_amdgcn_mfma_f32_16x16x32_bf16(ah[kf], bl[nf][kf], acc[nf], 0, 0, 0);
#pragma unroll
    for (int kf = 0; kf < 4; ++kf)
#pragma unroll
      for (int nf = 0; nf < 4; ++nf)
        acc[nf] = __builtin_amdgcn_mfma_f32_16x16x32_bf16(al[kf], bh[nf][kf], acc[nf], 0, 0, 0);

    if (lane < 16) {
      float v0 = acc[0][0] + pj0;
      float v1 = acc[1][0] + pj1;
      float v2 = acc[2][0] + pj2;
      float v3 = acc[3][0] + pj3;
      gates[wv * 64 + lane]      = isg ? tanhf(v0) : 1.f / (1.f + expf(-v0));
      gates[wv * 64 + 16 + lane] = isg ? tanhf(v1) : 1.f / (1.f + expf(-v1));
      gates[wv * 64 + 32 + lane] = isg ? tanhf(v2) : 1.f / (1.f + expf(-v2));
      gates[wv * 64 + 48 + lane] = isg ? tanhf(v3) : 1.f / (1.f + expf(-v3));
    }
    __syncthreads();
    if (tid < H_) {
      float gi = gates[tid],       gf = gates[tid + 128];
      float gg = gates[tid + 256], go = gates[tid + 384];
      float cn = gf * c + gi * gg;
      float hn = go * tanhf(cn);
      bool  m  = (t < len);
      c = m ? cn : c;
      float hv = m ? hn : h32[tid];
      h32[tid] = hv;
      unsigned short hi = bf16_rnd(hv);
      hhi[tid] = hi;
      hlo[tid] = bf16_rnd(hv - bf16_val(hi));
      hs[(size_t)(b * T_ + t) * 256 + dir * H_ + tid] = m ? hn : 0.f;
    }
    __syncthreads();
    tc += stp;
  }
  if (tid < H_) {
    sh[(dir * B_ + b) * H_ + tid] = h32[tid];
    sc[(dir * B_ + b) * H_ + tid] = c;
  }
}

// ---------------------------------------------------------------------------
// Kernel 3: emissions em[m][k] = hs[m][:] . W_out[k][:] + b_out[k]
// ---------------------------------------------------------------------------
__global__ __launch_bounds__(256)
void emis_kernel(const float* __restrict__ hs, const float* __restrict__ Wout,
                 const float* __restrict__ bout, float* __restrict__ em)
{
  __shared__ __align__(16) float Wl[K_ * 256];
  const int tid = threadIdx.x;
  for (int i = tid; i < K_ * 256; i += 256) Wl[i] = Wout[i];
  __syncthreads();
  const int m = blockIdx.x * 256 + tid;
  const float* h = hs + (size_t)m * 256;
  float acc[K_] = {};
#pragma unroll 4
  for (int kk = 0; kk < 64; ++kk) {
    float4 h4 = *(const float4*)(h + kk * 4);
#pragma unroll
    for (int k9 = 0; k9 < K_; ++k9) {
      float4 w4 = *(const float4*)&Wl[k9 * 256 + kk * 4];
      acc[k9] += h4.x * w4.x + h4.y * w4.y + h4.z * w4.z + h4.w * w4.w;
    }
  }
#pragma unroll
  for (int k9 = 0; k9 < K_; ++k9) em[(size_t)m * K_ + k9] = acc[k9] + bout[k9];
}

// ---------------------------------------------------------------------------
// Kernel 4: Viterbi decode, one 64-lane wave per batch element.
// ---------------------------------------------------------------------------
__global__ __launch_bounds__(64)
void viterbi_kernel(const float* __restrict__ em, const int* __restrict__ lengths,
                    const float* __restrict__ st, const float* __restrict__ en,
                    const float* __restrict__ trans, int* __restrict__ tags)
{
  const int b    = blockIdx.x;
  const int lane = threadIdx.x;
  __shared__ unsigned char hist[(T_ - 1) * 16];
  const int len = lengths[b];
  float tr[K_];
#pragma unroll
  for (int j = 0; j < K_; ++j) tr[j] = (lane < K_) ? trans[j * K_ + lane] : 0.f;
  float s = (lane < K_) ? st[lane] + em[(size_t)(b * T_) * K_ + lane] : -1e30f;
  for (int t = 1; t < len; ++t) {
    float best = -1e30f; int bj = 0;
#pragma unroll
    for (int j = 0; j < K_; ++j) {
      float v = __shfl(s, j) + tr[j];
      if (v > best) { best = v; bj = j; }    // strict > == first-max (argmax)
    }
    if (lane < K_) {
      s = best + em[(size_t)(b * T_ + t) * K_ + lane];
      hist[(t - 1) * 16 + lane] = (unsigned char)bj;
    }
  }
  float fs = (lane < K_) ? s + en[lane] : -1e30f;
  float best = -1e30f; int last = 0;
#pragma unroll
  for (int j = 0; j < K_; ++j) {
    float v = __shfl(fs, j);
    if (v > best) { best = v; last = j; }
  }
  __syncthreads();                            // hist visible to lane 0
  if (lane == 0) {
    int tag = last;
    tags[b * T_ + len - 1] = tag;
    for (int t = len - 2; t >= 0; --t) {
      tag = hist[t * 16 + tag];
      tags[b * T_ + t] = tag;
    }
  }
  for (int t = len + lane; t < T_; t += 64) tags[b * T_ + t] = 0;
}

// ---------------------------------------------------------------------------
extern "C" void kernel_launch(void* const* d_in, const int* in_sizes, int n_in,
                              void* d_out, int out_size, void* d_ws, size_t ws_size,
                              hipStream_t stream)
{
  const int*   sent  = (const int*)d_in[0];
  const int*   lens  = (const int*)d_in[1];
  const float* embed = (const float*)d_in[2];
  const float* Wif   = (const float*)d_in[3];
  const float* Whf   = (const float*)d_in[4];
  const float* bif   = (const float*)d_in[5];
  const float* bhf   = (const float*)d_in[6];
  const float* Wib   = (const float*)d_in[7];
  const float* Whb   = (const float*)d_in[8];
  const float* bib   = (const float*)d_in[9];
  const float* bhb   = (const float*)d_in[10];
  const float* Wout  = (const float*)d_in[11];
  const float* bout  = (const float*)d_in[12];
  const float* stt   = (const float*)d_in[13];
  const float* ent   = (const float*)d_in[14];
  const float* trans = (const float*)d_in[15];
  int* tags = (int*)d_out;

  // workspace (floats): hs | em | sh | sc | wswz(ih+hh) | bsum | proj(chunk)
  float* ws   = (float*)d_ws;
  float* hs   = ws;                                  // B*T*256   (67.1 MB)
  float* em   = hs + (size_t)B_ * T_ * 256;          // B*T*9     ( 2.4 MB)
  float* sh   = em + (size_t)B_ * T_ * K_;
  float* sc   = sh + (size_t)2 * B_ * H_;
  unsigned short* wswz = (unsigned short*)(sc + (size_t)2 * B_ * H_); // 524288 shorts (1 MB)
  float* bsum = (float*)(wswz + 524288);             // 1024 floats
  float* proj = bsum + 1024;
  const size_t fixed_bytes = (size_t)((char*)proj - (char*)ws);

  // largest time-chunk whose proj buffer fits the workspace (floor at 64)
  int Tc = 512, tcshift = 9;
  while (Tc > 64 && fixed_bytes + (size_t)B_ * Tc * 1024 * sizeof(float) > ws_size) {
    Tc >>= 1; tcshift--;
  }

  hipLaunchKernelGGL(prep_weights, dim3(128), dim3(256), 0, stream,
                     Wif, Wib, Whf, Whb, bif, bhf, bib, bhb, wswz, bsum);

  const unsigned short* wih_swz = wswz;
  const unsigned short* whh_swz = wswz + 262144;
  const int nch = T_ / Tc;
  for (int c2 = 0; c2 < nch; ++c2) {
    const int t0f = c2 * Tc;
    dim3 g1((B_ * Tc) >> 8, 2);
    hipLaunchKernelGGL(proj_mfma4, g1, dim3(256), 0, stream,
                       sent, embed, wih_swz, bsum, proj, t0f, Tc, tcshift);
    dim3 g2(2, B_);
    hipLaunchKernelGGL(lstm_mfma, g2, dim3(512), 0, stream,
                       proj, whh_swz, lens, hs, sh, sc, t0f, Tc, (int)(c2 == 0));
  }
  hipLaunchKernelGGL(emis_kernel, dim3((B_ * T_) / 256), dim3(256), 0, stream,
                     hs, Wout, bout, em);
  hipLaunchKernelGGL(viterbi_kernel, dim3(B_), dim3(64), 0, stream,
                     em, lens, stt, ent, trans, tags);
}